// Round 14
// baseline (98.767 us; speedup 1.0000x reference)
//
#include <hip/hip_runtime.h>
#include <hip/hip_bf16.h>
#include <stdint.h>

typedef __bf16 bf16_t;
typedef __bf16 bf16x2 __attribute__((ext_vector_type(2)));
typedef __bf16 bf16x4 __attribute__((ext_vector_type(4)));
typedef __bf16 bf16x8 __attribute__((ext_vector_type(8)));
typedef float f32x4 __attribute__((ext_vector_type(4)));

#define MFMA(a, b, c) __builtin_amdgcn_mfma_f32_16x16x32_bf16(a, b, c, 0, 0, 0)

#if __has_builtin(__builtin_amdgcn_exp2f)
#define FEXP2 __builtin_amdgcn_exp2f
#else
#define FEXP2 exp2f
#endif

// async global->LDS, 16B per lane; lds dest is wave-uniform base + lane*16
__device__ __forceinline__ void g2lds16(const void* g, void* l) {
  __builtin_amdgcn_global_load_lds(
      reinterpret_cast<const __attribute__((address_space(1))) unsigned int*>(
          reinterpret_cast<uintptr_t>(g)),
      reinterpret_cast<__attribute__((address_space(3))) unsigned int*>(
          reinterpret_cast<uintptr_t>(l)),
      16, 0, 0);
}

__device__ __forceinline__ unsigned cvtpk(float lo, float hi) {
  unsigned r;
  asm("v_cvt_pk_bf16_f32 %0, %1, %2" : "=v"(r) : "v"(lo), "v"(hi));
  return r;
}

// A.hi32 <-> B.lo32  (after: A = [A.lo, B.lo], B = [A.hi, B.hi])
__device__ __forceinline__ void lane_swap32(unsigned& a, unsigned& b) {
#if __has_builtin(__builtin_amdgcn_permlane32_swap)
  typedef int i32x2 __attribute__((ext_vector_type(2)));
  i32x2 r = __builtin_amdgcn_permlane32_swap((int)a, (int)b, false, false);
  a = (unsigned)r[0];
  b = (unsigned)r[1];
#else
  asm("v_permlane32_swap_b32 %0, %1" : "+v"(a), "+v"(b));
#endif
}

// per-32: A.rows16-31 <-> B.rows0-15
__device__ __forceinline__ void lane_swap16(unsigned& a, unsigned& b) {
#if __has_builtin(__builtin_amdgcn_permlane16_swap)
  typedef int i32x2 __attribute__((ext_vector_type(2)));
  i32x2 r = __builtin_amdgcn_permlane16_swap((int)a, (int)b, false, false);
  a = (unsigned)r[0];
  b = (unsigned)r[1];
#else
  asm("v_permlane16_swap_b32 %0, %1" : "+v"(a), "+v"(b));
#endif
}

// Op partial pointer for split s: dead prep regions {0,4,8}MB + tail {25..41}MB
__device__ __host__ __forceinline__ char* op_ptr(char* wsb, int s) {
  return s < 3 ? wsb + ((size_t)s << 22)
               : wsb + ((size_t)(25 + ((s - 3) << 2)) << 20);
}

// ---------------- fused prep kernel ----------------
__global__ __launch_bounds__(256) void k_prep(const float* __restrict__ x,
                                              const float* __restrict__ Wq,
                                              const float* __restrict__ Wk,
                                              const float* __restrict__ Wv,
                                              const float* __restrict__ Wo,
                                              const float* __restrict__ Pout,
                                              const float* __restrict__ Pinv,
                                              bf16_t* __restrict__ Xbf,
                                              bf16_t* __restrict__ WqT,
                                              bf16_t* __restrict__ WkT,
                                              bf16_t* __restrict__ WvT,
                                              bf16_t* __restrict__ WoT) {
  const int bid = blockIdx.x;
  if (bid < 2048) {
    int i = (bid * 256 + threadIdx.x) * 4;
    float4 v = *reinterpret_cast<const float4*>(x + i);
    bf16x4 o;
    o[0] = (bf16_t)v.x; o[1] = (bf16_t)v.y; o[2] = (bf16_t)v.z; o[3] = (bf16_t)v.w;
    *reinterpret_cast<bf16x4*>(Xbf + i) = o;
  } else if (bid < 3072) {
    int idx = (bid - 2048) * 256 + threadIdx.x;  // 8*512*64
    int t = idx >> 15;
    int n = (idx >> 6) & 511;
    int k0 = (idx & 63) << 3;
    int dq4 = (n >> 2) << 2;
    int g = n & 3;
    float pq[4], pk[4];
#pragma unroll
    for (int h = 0; h < 4; ++h) {
      pq[h] = Pinv[t * 16 + h * 4 + g];
      pk[h] = Pout[t * 16 + h * 4 + g];
    }
    bf16x8 oq, ok;
#pragma unroll
    for (int j = 0; j < 8; ++j) {
      const float4 wq = *reinterpret_cast<const float4*>(Wq + (size_t)(k0 + j) * 512 + dq4);
      const float4 wk = *reinterpret_cast<const float4*>(Wk + (size_t)(k0 + j) * 512 + dq4);
      oq[j] = (bf16_t)((wq.x * pq[0] + wq.y * pq[1] + wq.z * pq[2] + wq.w * pq[3]) * 0.1803368801f);
      ok[j] = (bf16_t)(wk.x * pk[0] + wk.y * pk[1] + wk.z * pk[2] + wk.w * pk[3]);
    }
    size_t o = ((size_t)t * 512 + n) * 512 + k0;
    *reinterpret_cast<bf16x8*>(WqT + o) = oq;
    *reinterpret_cast<bf16x8*>(WkT + o) = ok;
  } else {
    int idx = (bid - 3072) * 256 + threadIdx.x;  // 2*512*64
    int mat = idx >> 15;
    int n = (idx >> 6) & 511;
    int k0 = (idx & 63) << 3;
    const float* W = mat ? Wo : Wv;
    bf16_t* T = mat ? WoT : WvT;
    bf16x8 o;
#pragma unroll
    for (int j = 0; j < 8; ++j) o[j] = (bf16_t)W[(size_t)(k0 + j) * 512 + n];
    *reinterpret_cast<bf16x8*>(T + (size_t)n * 512 + k0) = o;
  }
}

// ---------------- projection GEMM (Q,K,V), 128x64, grid 768 (round-9-proven) ----------------
__global__ __launch_bounds__(256) void k_gemm_qkv(const bf16_t* __restrict__ Xbf,
                                                  const bf16_t* __restrict__ WqT,
                                                  const bf16_t* __restrict__ WkT,
                                                  const bf16_t* __restrict__ WvT,
                                                  bf16_t* __restrict__ Qh,
                                                  bf16_t* __restrict__ Kh,
                                                  bf16_t* __restrict__ Vt) {
  __shared__ bf16_t lA[128 * 64];
  __shared__ bf16_t lB[64 * 64];
  const int m0 = blockIdx.x * 128, n0 = blockIdx.y * 64;
  const int mat = blockIdx.z;
  const int frame = m0 >> 9;
  const bf16_t* WT = (mat == 0) ? (WqT + (size_t)frame * 512 * 512)
                   : (mat == 1) ? (WkT + (size_t)frame * 512 * 512)
                                : WvT;
  const int tid = threadIdx.x, lane = tid & 63, wid = tid >> 6;
  const int wr = wid >> 1, wc = wid & 1;
  const int l15 = lane & 15, lg = lane >> 4;
  const int srow = lane >> 3;
  const int scol = ((lane & 7) ^ (lane >> 3)) << 3;

  f32x4 acc[4][2] = {};

  for (int kt = 0; kt < 512; kt += 64) {
#pragma unroll
    for (int i = 0; i < 4; ++i) {
      int chunk = wid * 4 + i;
      int row = chunk * 8 + srow;
      g2lds16(Xbf + (size_t)(m0 + row) * 512 + kt + scol, lA + chunk * 512);
    }
#pragma unroll
    for (int i = 0; i < 2; ++i) {
      int chunk = wid * 2 + i;
      int row = chunk * 8 + srow;
      g2lds16(WT + (size_t)(n0 + row) * 512 + kt + scol, lB + chunk * 512);
    }
    __syncthreads();
#pragma unroll
    for (int kk = 0; kk < 2; ++kk) {
      bf16x8 af[4], bw[2];
      int c16 = ((4 * kk + lg) ^ (l15 & 7)) << 3;
#pragma unroll
      for (int i = 0; i < 4; ++i)
        af[i] = *reinterpret_cast<const bf16x8*>(lA + (wr * 64 + i * 16 + l15) * 64 + c16);
#pragma unroll
      for (int j = 0; j < 2; ++j)
        bw[j] = *reinterpret_cast<const bf16x8*>(lB + (wc * 32 + j * 16 + l15) * 64 + c16);
#pragma unroll
      for (int i = 0; i < 4; ++i)
#pragma unroll
        for (int j = 0; j < 2; ++j)
          acc[i][j] = MFMA(af[i], bw[j], acc[i][j]);
    }
    __syncthreads();
  }

#pragma unroll
  for (int i = 0; i < 4; ++i)
#pragma unroll
    for (int j = 0; j < 2; ++j)
#pragma unroll
      for (int r = 0; r < 4; ++r) {
        int s = m0 + wr * 64 + i * 16 + lg * 4 + r;
        int n = n0 + wc * 32 + j * 16 + l15;
        bf16_t v = (bf16_t)acc[i][j][r];
        if (mat == 2) {
          Vt[(size_t)n * 4096 + s] = v;                               // (h,d,s)
        } else if (mat == 0) {
          Qh[((size_t)(n >> 6) * 4096 + s) * 64 + (n & 63)] = v;      // (h,s,d)
        } else {
          Kh[((size_t)(n >> 6) * 4096 + s) * 64 + (n & 63)] = v;
        }
      }
}

// ---------------- flash attention, K-split-8 partials ----------------
// block: 4 waves x 64 q = 256 q rows; grid (16 qtiles, 8 heads, 8 ksplits) = 1024
// = 4 blocks/CU (32KB LDS) AND the 64q/wave LDS-read amortization — combining
// the two individually-proven levers of rounds 8 and 9. Each block scans 512
// keys in 8 tiles, K/V double-buffered. No max tracking (bounded scores):
// P = 2^s. l via ones-MFMA; in-register P via cvt_pk + permlane swaps.
__global__ __launch_bounds__(256, 2) void k_attn(const bf16_t* __restrict__ Qh,
                                                 const bf16_t* __restrict__ Kh,
                                                 const bf16_t* __restrict__ Vt,
                                                 char* __restrict__ wsb,
                                                 float* __restrict__ Lp) {
  __shared__ bf16_t lK[2][64 * 64];   // 16 KB
  __shared__ bf16_t lV[2][64 * 64];   // 16 KB
  const int h = blockIdx.y;
  const int ks = blockIdx.z;
  const int q0 = blockIdx.x * 256;
  const int tid = threadIdx.x, lane = tid & 63, wid = tid >> 6;
  const int l15 = lane & 15, lg = lane >> 4;
  const int srow = lane >> 3;
  const int scol = ((lane & 7) ^ (lane >> 3)) << 3;

  bf16_t* Op = (bf16_t*)op_ptr(wsb, ks);

  bf16x8 qf[4][2];
#pragma unroll
  for (int g = 0; g < 4; ++g) {
    const bf16_t* Qp = Qh + ((size_t)h * 4096 + q0 + wid * 64 + g * 16 + l15) * 64;
#pragma unroll
    for (int kk = 0; kk < 2; ++kk)
      qf[g][kk] = *reinterpret_cast<const bf16x8*>(Qp + kk * 32 + lg * 8);
  }

  bf16x8 onesf;
#pragma unroll
  for (int j = 0; j < 8; ++j) onesf[j] = (bf16_t)1.0f;

  const bf16_t* Kb = Kh + ((size_t)h * 4096 + ks * 512) * 64;
  const bf16_t* Vb = Vt + (size_t)h * 64 * 4096 + ks * 512;

  f32x4 oT[4][4] = {};
  f32x4 lac[4] = {};

  auto stage = [&](int buf, int kt) {
#pragma unroll
    for (int i = 0; i < 2; ++i) {
      int chunk = wid * 2 + i;
      int row = chunk * 8 + srow;
      g2lds16(Kb + (size_t)(kt + row) * 64 + scol, &lK[buf][chunk * 512]);
      g2lds16(Vb + (size_t)row * 4096 + kt + scol, &lV[buf][chunk * 512]);
    }
  };

  stage(0, 0);
  __syncthreads();  // compiler drains vmcnt(0) before barrier

  for (int t = 0; t < 8; ++t) {
    const int cur = t & 1;
    if (t < 7) stage(cur ^ 1, (t + 1) * 64);

    // S^T = K . Q^T : rows = keys, col = q (lane-local l15); 4 q-groups per kf
    f32x4 st[4][4] = {};
    __builtin_amdgcn_s_setprio(1);
#pragma unroll
    for (int kk = 0; kk < 2; ++kk)
#pragma unroll
      for (int mb = 0; mb < 4; ++mb) {
        bf16x8 kf = *reinterpret_cast<const bf16x8*>(
            &lK[cur][(mb * 16 + l15) * 64 + (((kk * 4 + lg) ^ (l15 & 7)) << 3)]);
        st[0][mb] = MFMA(kf, qf[0][kk], st[0][mb]);
        st[1][mb] = MFMA(kf, qf[1][kk], st[1][mb]);
        st[2][mb] = MFMA(kf, qf[2][kk], st[2][mb]);
        st[3][mb] = MFMA(kf, qf[3][kk], st[3][mb]);
      }
    __builtin_amdgcn_s_setprio(0);

    // P = 2^s directly (no max tracking; bounded scores)
#pragma unroll
    for (int g = 0; g < 4; ++g)
#pragma unroll
      for (int mb = 0; mb < 4; ++mb)
#pragma unroll
        for (int r = 0; r < 4; ++r)
          st[g][mb][r] = FEXP2(st[g][mb][r]);

    // P -> bf16 B-frags in-register (round-6-proven permutation)
    bf16x8 pb[4][2];
#pragma unroll
    for (int g = 0; g < 4; ++g)
#pragma unroll
      for (int kk = 0; kk < 2; ++kk) {
        unsigned A  = cvtpk(st[g][2 * kk][0],     st[g][2 * kk][1]);
        unsigned Ap = cvtpk(st[g][2 * kk][2],     st[g][2 * kk][3]);
        unsigned B  = cvtpk(st[g][2 * kk + 1][0], st[g][2 * kk + 1][1]);
        unsigned Bp = cvtpk(st[g][2 * kk + 1][2], st[g][2 * kk + 1][3]);
        lane_swap32(A, B);
        lane_swap16(A, B);
        lane_swap32(Ap, Bp);
        lane_swap16(Ap, Bp);
        union { unsigned u[4]; bf16x8 v; } pu;
        pu.u[0] = A; pu.u[1] = Ap; pu.u[2] = B; pu.u[3] = Bp;
        pb[g][kk] = pu.v;
      }

    // O^T += V^T . P^T ; l via ones-row MFMA; each vf feeds 4 q-groups
    __builtin_amdgcn_s_setprio(1);
#pragma unroll
    for (int kk = 0; kk < 2; ++kk) {
      lac[0] = MFMA(onesf, pb[0][kk], lac[0]);
      lac[1] = MFMA(onesf, pb[1][kk], lac[1]);
      lac[2] = MFMA(onesf, pb[2][kk], lac[2]);
      lac[3] = MFMA(onesf, pb[3][kk], lac[3]);
#pragma unroll
      for (int hb = 0; hb < 4; ++hb) {
        bf16x8 vf = *reinterpret_cast<const bf16x8*>(
            &lV[cur][(hb * 16 + l15) * 64 + (((kk * 4 + lg) ^ (l15 & 7)) << 3)]);
        oT[0][hb] = MFMA(vf, pb[0][kk], oT[0][hb]);
        oT[1][hb] = MFMA(vf, pb[1][kk], oT[1][hb]);
        oT[2][hb] = MFMA(vf, pb[2][kk], oT[2][hb]);
        oT[3][hb] = MFMA(vf, pb[3][kk], oT[3][hb]);
      }
    }
    __builtin_amdgcn_s_setprio(0);
    __syncthreads();
  }

  // epilogue: store unnormalized partials (l replicated in all lac rows)
#pragma unroll
  for (int g = 0; g < 4; ++g) {
    int q = q0 + wid * 64 + g * 16 + l15;
    size_t rbase = ((size_t)ks * 8 + h) * 4096 + q;
    size_t obase = ((size_t)h * 4096 + q) * 64;
    if (lg == 0) Lp[rbase] = lac[g][0];
#pragma unroll
    for (int hb = 0; hb < 4; ++hb) {
      bf16x4 ov;
#pragma unroll
      for (int r = 0; r < 4; ++r) ov[r] = (bf16_t)oT[g][hb][r];
      *reinterpret_cast<bf16x4*>(Op + obase + hb * 16 + lg * 4) = ov;
    }
  }
}

// ---------------- K-split merge (8 splits, unweighted; bf16x8-vectorized) ----------------
__global__ __launch_bounds__(256) void k_merge(char* __restrict__ wsb,
                                               const float* __restrict__ Lp,
                                               bf16_t* __restrict__ Obf) {
  int idx = blockIdx.x * 256 + threadIdx.x;  // 8*4096*8 threads
  int d8 = (idx & 7) << 3;
  int row = idx >> 3;  // h*4096 + q
  float l = 0.f;
  float o[8] = {};
#pragma unroll
  for (int s = 0; s < 8; ++s) {
    const bf16_t* Ops = (const bf16_t*)op_ptr(wsb, s);
    l += Lp[s * 32768 + row];
    bf16x8 v = *reinterpret_cast<const bf16x8*>(Ops + (size_t)row * 64 + d8);
#pragma unroll
    for (int j = 0; j < 8; ++j) o[j] += (float)v[j];
  }
  float rinv = 1.f / l;
  int h = row >> 12, q = row & 4095;
  bf16x8 ov;
#pragma unroll
  for (int j = 0; j < 8; ++j) ov[j] = (bf16_t)(o[j] * rinv);
  *reinterpret_cast<bf16x8*>(Obf + (size_t)q * 512 + h * 64 + d8) = ov;
}

// ---------------- output GEMM + bias + residual ----------------
__global__ __launch_bounds__(256) void k_gemm_out(const bf16_t* __restrict__ Obf,
                                                  const bf16_t* __restrict__ WoT,
                                                  const float* __restrict__ bo,
                                                  const float* __restrict__ resid,
                                                  float* __restrict__ out) {
  __shared__ bf16_t lA[64 * 64];
  __shared__ bf16_t lB[64 * 64];
  const int m0 = blockIdx.x * 64, n0 = blockIdx.y * 64;
  const int tid = threadIdx.x, lane = tid & 63, wid = tid >> 6;
  const int wr = wid >> 1, wc = wid & 1;
  const int l15 = lane & 15, lg = lane >> 4;
  const int srow = lane >> 3;
  const int scol = ((lane & 7) ^ (lane >> 3)) << 3;

  f32x4 acc[2][2] = {};

  for (int kt = 0; kt < 512; kt += 64) {
#pragma unroll
    for (int i = 0; i < 2; ++i) {
      int chunk = wid * 2 + i;
      int row = chunk * 8 + srow;
      g2lds16(Obf + (size_t)(m0 + row) * 512 + kt + scol, lA + chunk * 512);
      g2lds16(WoT + (size_t)(n0 + row) * 512 + kt + scol, lB + chunk * 512);
    }
    __syncthreads();
#pragma unroll
    for (int kk = 0; kk < 2; ++kk) {
      bf16x8 af[2], bw[2];
      int c16 = ((4 * kk + lg) ^ (l15 & 7)) << 3;
#pragma unroll
      for (int i = 0; i < 2; ++i) {
        af[i] = *reinterpret_cast<const bf16x8*>(lA + (wr * 32 + i * 16 + l15) * 64 + c16);
        bw[i] = *reinterpret_cast<const bf16x8*>(lB + (wc * 32 + i * 16 + l15) * 64 + c16);
      }
#pragma unroll
      for (int i = 0; i < 2; ++i)
#pragma unroll
        for (int j = 0; j < 2; ++j)
          acc[i][j] = MFMA(af[i], bw[j], acc[i][j]);
    }
    __syncthreads();
  }

#pragma unroll
  for (int i = 0; i < 2; ++i)
#pragma unroll
    for (int j = 0; j < 2; ++j)
#pragma unroll
      for (int r = 0; r < 4; ++r) {
        int s = m0 + wr * 32 + i * 16 + lg * 4 + r;
        int n = n0 + wc * 32 + j * 16 + l15;
        size_t o = (size_t)s * 512 + n;
        out[o] = acc[i][j][r] + bo[n] + resid[o];
      }
}

extern "C" void kernel_launch(void* const* d_in, const int* in_sizes, int n_in,
                              void* d_out, int out_size, void* d_ws, size_t ws_size,
                              hipStream_t stream) {
  const float* hs   = (const float*)d_in[0];
  const float* pout = (const float*)d_in[1];
  const float* pinv = (const float*)d_in[2];
  const float* Wq   = (const float*)d_in[3];
  const float* Wk   = (const float*)d_in[4];
  const float* Wv   = (const float*)d_in[5];
  const float* Wo   = (const float*)d_in[6];
  const float* bo   = (const float*)d_in[7];
  float* out = (float*)d_out;

  char* ws = (char*)d_ws;
  bf16_t* Xbf = (bf16_t*)(ws);                          // 4 MB   (Op[0] later)
  bf16_t* WqT = (bf16_t*)(ws + (4u << 20));             // 4 MB   (Op[1] later)
  bf16_t* WkT = (bf16_t*)(ws + (8u << 20));             // 4 MB   (Op[2] later)
  bf16_t* WvT = (bf16_t*)(ws + (12u << 20));            // 0.5 MB (dead after qkv)
  bf16_t* WoT = (bf16_t*)(ws + (12u << 20) + (512u << 10));  // 0.5 MB, live to end
  bf16_t* Qh  = (bf16_t*)(ws + (13u << 20));            // 4 MB (h,s,d); Obf reuses post-attn
  bf16_t* Kh  = (bf16_t*)(ws + (17u << 20));            // 4 MB (h,s,d)
  bf16_t* Vt  = (bf16_t*)(ws + (21u << 20));            // 4 MB (h,d,s)
  bf16_t* Obf = (bf16_t*)(ws + (13u << 20));            // reuse dead Qh region
  // Op splits: {0,4,8} MB (dead prep) + {25,29,33,37,41} MB tail; Lp at 45 MB
  float*  Lp  = (float*)(ws + (45u << 20));             // 8*8*4096 f32 = 1 MB -> peak 46 MB

  hipLaunchKernelGGL(k_prep, dim3(3328), dim3(256), 0, stream,
                     hs, Wq, Wk, Wv, Wo, pout, pinv, Xbf, WqT, WkT, WvT, WoT);
  hipLaunchKernelGGL(k_gemm_qkv, dim3(32, 8, 3), dim3(256), 0, stream,
                     Xbf, WqT, WkT, WvT, Qh, Kh, Vt);
  hipLaunchKernelGGL(k_attn, dim3(16, 8, 8), dim3(256), 0, stream, Qh, Kh, Vt, ws, Lp);
  hipLaunchKernelGGL(k_merge, dim3(1024), dim3(256), 0, stream, ws, Lp, Obf);
  hipLaunchKernelGGL(k_gemm_out, dim3(64, 8), dim3(256), 0, stream, Obf, WoT, bo, hs, out);
}

// Round 15
// 93.546 us; speedup vs baseline: 1.0558x; 1.0558x over previous
//
#include <hip/hip_runtime.h>
#include <hip/hip_bf16.h>
#include <stdint.h>

typedef __bf16 bf16_t;
typedef __bf16 bf16x2 __attribute__((ext_vector_type(2)));
typedef __bf16 bf16x4 __attribute__((ext_vector_type(4)));
typedef __bf16 bf16x8 __attribute__((ext_vector_type(8)));
typedef float f32x4 __attribute__((ext_vector_type(4)));

#define MFMA(a, b, c) __builtin_amdgcn_mfma_f32_16x16x32_bf16(a, b, c, 0, 0, 0)

#if __has_builtin(__builtin_amdgcn_exp2f)
#define FEXP2 __builtin_amdgcn_exp2f
#else
#define FEXP2 exp2f
#endif

// async global->LDS, 16B per lane; lds dest is wave-uniform base + lane*16
__device__ __forceinline__ void g2lds16(const void* g, void* l) {
  __builtin_amdgcn_global_load_lds(
      reinterpret_cast<const __attribute__((address_space(1))) unsigned int*>(
          reinterpret_cast<uintptr_t>(g)),
      reinterpret_cast<__attribute__((address_space(3))) unsigned int*>(
          reinterpret_cast<uintptr_t>(l)),
      16, 0, 0);
}

__device__ __forceinline__ unsigned cvtpk(float lo, float hi) {
  unsigned r;
  asm("v_cvt_pk_bf16_f32 %0, %1, %2" : "=v"(r) : "v"(lo), "v"(hi));
  return r;
}

// A.hi32 <-> B.lo32  (after: A = [A.lo, B.lo], B = [A.hi, B.hi])
__device__ __forceinline__ void lane_swap32(unsigned& a, unsigned& b) {
#if __has_builtin(__builtin_amdgcn_permlane32_swap)
  typedef int i32x2 __attribute__((ext_vector_type(2)));
  i32x2 r = __builtin_amdgcn_permlane32_swap((int)a, (int)b, false, false);
  a = (unsigned)r[0];
  b = (unsigned)r[1];
#else
  asm("v_permlane32_swap_b32 %0, %1" : "+v"(a), "+v"(b));
#endif
}

// per-32: A.rows16-31 <-> B.rows0-15
__device__ __forceinline__ void lane_swap16(unsigned& a, unsigned& b) {
#if __has_builtin(__builtin_amdgcn_permlane16_swap)
  typedef int i32x2 __attribute__((ext_vector_type(2)));
  i32x2 r = __builtin_amdgcn_permlane16_swap((int)a, (int)b, false, false);
  a = (unsigned)r[0];
  b = (unsigned)r[1];
#else
  asm("v_permlane16_swap_b32 %0, %1" : "+v"(a), "+v"(b));
#endif
}

// ---------------- fused prep kernel ----------------
__global__ __launch_bounds__(256) void k_prep(const float* __restrict__ x,
                                              const float* __restrict__ Wq,
                                              const float* __restrict__ Wk,
                                              const float* __restrict__ Wv,
                                              const float* __restrict__ Wo,
                                              const float* __restrict__ Pout,
                                              const float* __restrict__ Pinv,
                                              bf16_t* __restrict__ Xbf,
                                              bf16_t* __restrict__ WqT,
                                              bf16_t* __restrict__ WkT,
                                              bf16_t* __restrict__ WvT,
                                              bf16_t* __restrict__ WoT) {
  const int bid = blockIdx.x;
  if (bid < 2048) {
    int i = (bid * 256 + threadIdx.x) * 4;
    float4 v = *reinterpret_cast<const float4*>(x + i);
    bf16x4 o;
    o[0] = (bf16_t)v.x; o[1] = (bf16_t)v.y; o[2] = (bf16_t)v.z; o[3] = (bf16_t)v.w;
    *reinterpret_cast<bf16x4*>(Xbf + i) = o;
  } else if (bid < 3072) {
    int idx = (bid - 2048) * 256 + threadIdx.x;  // 8*512*64
    int t = idx >> 15;
    int n = (idx >> 6) & 511;
    int k0 = (idx & 63) << 3;
    int dq4 = (n >> 2) << 2;
    int g = n & 3;
    float pq[4], pk[4];
#pragma unroll
    for (int h = 0; h < 4; ++h) {
      pq[h] = Pinv[t * 16 + h * 4 + g];
      pk[h] = Pout[t * 16 + h * 4 + g];
    }
    bf16x8 oq, ok;
#pragma unroll
    for (int j = 0; j < 8; ++j) {
      const float4 wq = *reinterpret_cast<const float4*>(Wq + (size_t)(k0 + j) * 512 + dq4);
      const float4 wk = *reinterpret_cast<const float4*>(Wk + (size_t)(k0 + j) * 512 + dq4);
      oq[j] = (bf16_t)((wq.x * pq[0] + wq.y * pq[1] + wq.z * pq[2] + wq.w * pq[3]) * 0.1803368801f);
      ok[j] = (bf16_t)(wk.x * pk[0] + wk.y * pk[1] + wk.z * pk[2] + wk.w * pk[3]);
    }
    size_t o = ((size_t)t * 512 + n) * 512 + k0;
    *reinterpret_cast<bf16x8*>(WqT + o) = oq;
    *reinterpret_cast<bf16x8*>(WkT + o) = ok;
  } else {
    int idx = (bid - 3072) * 256 + threadIdx.x;  // 2*512*64
    int mat = idx >> 15;
    int n = (idx >> 6) & 511;
    int k0 = (idx & 63) << 3;
    const float* W = mat ? Wo : Wv;
    bf16_t* T = mat ? WoT : WvT;
    bf16x8 o;
#pragma unroll
    for (int j = 0; j < 8; ++j) o[j] = (bf16_t)W[(size_t)(k0 + j) * 512 + n];
    *reinterpret_cast<bf16x8*>(T + (size_t)n * 512 + k0) = o;
  }
}

// ---------------- projection GEMM (Q,K,V), 128x64, grid 768 (round-9-proven) ----------------
__global__ __launch_bounds__(256) void k_gemm_qkv(const bf16_t* __restrict__ Xbf,
                                                  const bf16_t* __restrict__ WqT,
                                                  const bf16_t* __restrict__ WkT,
                                                  const bf16_t* __restrict__ WvT,
                                                  bf16_t* __restrict__ Qh,
                                                  bf16_t* __restrict__ Kh,
                                                  bf16_t* __restrict__ Vt) {
  __shared__ bf16_t lA[128 * 64];
  __shared__ bf16_t lB[64 * 64];
  const int m0 = blockIdx.x * 128, n0 = blockIdx.y * 64;
  const int mat = blockIdx.z;
  const int frame = m0 >> 9;
  const bf16_t* WT = (mat == 0) ? (WqT + (size_t)frame * 512 * 512)
                   : (mat == 1) ? (WkT + (size_t)frame * 512 * 512)
                                : WvT;
  const int tid = threadIdx.x, lane = tid & 63, wid = tid >> 6;
  const int wr = wid >> 1, wc = wid & 1;
  const int l15 = lane & 15, lg = lane >> 4;
  const int srow = lane >> 3;
  const int scol = ((lane & 7) ^ (lane >> 3)) << 3;

  f32x4 acc[4][2] = {};

  for (int kt = 0; kt < 512; kt += 64) {
#pragma unroll
    for (int i = 0; i < 4; ++i) {
      int chunk = wid * 4 + i;
      int row = chunk * 8 + srow;
      g2lds16(Xbf + (size_t)(m0 + row) * 512 + kt + scol, lA + chunk * 512);
    }
#pragma unroll
    for (int i = 0; i < 2; ++i) {
      int chunk = wid * 2 + i;
      int row = chunk * 8 + srow;
      g2lds16(WT + (size_t)(n0 + row) * 512 + kt + scol, lB + chunk * 512);
    }
    __syncthreads();
#pragma unroll
    for (int kk = 0; kk < 2; ++kk) {
      bf16x8 af[4], bw[2];
      int c16 = ((4 * kk + lg) ^ (l15 & 7)) << 3;
#pragma unroll
      for (int i = 0; i < 4; ++i)
        af[i] = *reinterpret_cast<const bf16x8*>(lA + (wr * 64 + i * 16 + l15) * 64 + c16);
#pragma unroll
      for (int j = 0; j < 2; ++j)
        bw[j] = *reinterpret_cast<const bf16x8*>(lB + (wc * 32 + j * 16 + l15) * 64 + c16);
#pragma unroll
      for (int i = 0; i < 4; ++i)
#pragma unroll
        for (int j = 0; j < 2; ++j)
          acc[i][j] = MFMA(af[i], bw[j], acc[i][j]);
    }
    __syncthreads();
  }

#pragma unroll
  for (int i = 0; i < 4; ++i)
#pragma unroll
    for (int j = 0; j < 2; ++j)
#pragma unroll
      for (int r = 0; r < 4; ++r) {
        int s = m0 + wr * 64 + i * 16 + lg * 4 + r;
        int n = n0 + wc * 32 + j * 16 + l15;
        bf16_t v = (bf16_t)acc[i][j][r];
        if (mat == 2) {
          Vt[(size_t)n * 4096 + s] = v;                               // (h,d,s)
        } else if (mat == 0) {
          Qh[((size_t)(n >> 6) * 4096 + s) * 64 + (n & 63)] = v;      // (h,s,d)
        } else {
          Kh[((size_t)(n >> 6) * 4096 + s) * 64 + (n & 63)] = v;
        }
      }
}

// ---------------- flash attention, K-split partials (round-9-exact) ----------------
// block: 4 waves x 64 q = 256 q rows; grid (16 qtiles, 8 heads, 4 ksplits) = 512.
// K/V double-buffered (32KB). No max tracking (bounded scores): P = 2^s.
// l via ones-MFMA; in-register P via cvt_pk + permlane swaps.
__global__ __launch_bounds__(256, 2) void k_attn(const bf16_t* __restrict__ Qh,
                                                 const bf16_t* __restrict__ Kh,
                                                 const bf16_t* __restrict__ Vt,
                                                 char* __restrict__ wsb,
                                                 float* __restrict__ Lp) {
  __shared__ bf16_t lK[2][64 * 64];   // 16 KB
  __shared__ bf16_t lV[2][64 * 64];   // 16 KB
  const int h = blockIdx.y;
  const int ks = blockIdx.z;
  const int q0 = blockIdx.x * 256;
  const int tid = threadIdx.x, lane = tid & 63, wid = tid >> 6;
  const int l15 = lane & 15, lg = lane >> 4;
  const int srow = lane >> 3;
  const int scol = ((lane & 7) ^ (lane >> 3)) << 3;

  // Op partials scattered over dead prep regions (ks 0..2) + tail (ks 3)
  bf16_t* Op = (bf16_t*)(ks < 3 ? wsb + ((size_t)ks << 22) : wsb + (29u << 20));

  bf16x8 qf[4][2];
#pragma unroll
  for (int g = 0; g < 4; ++g) {
    const bf16_t* Qp = Qh + ((size_t)h * 4096 + q0 + wid * 64 + g * 16 + l15) * 64;
#pragma unroll
    for (int kk = 0; kk < 2; ++kk)
      qf[g][kk] = *reinterpret_cast<const bf16x8*>(Qp + kk * 32 + lg * 8);
  }

  bf16x8 onesf;
#pragma unroll
  for (int j = 0; j < 8; ++j) onesf[j] = (bf16_t)1.0f;

  const bf16_t* Kb = Kh + ((size_t)h * 4096 + ks * 1024) * 64;
  const bf16_t* Vb = Vt + (size_t)h * 64 * 4096 + ks * 1024;

  f32x4 oT[4][4] = {};
  f32x4 lac[4] = {};

  auto stage = [&](int buf, int kt) {
#pragma unroll
    for (int i = 0; i < 2; ++i) {
      int chunk = wid * 2 + i;
      int row = chunk * 8 + srow;
      g2lds16(Kb + (size_t)(kt + row) * 64 + scol, &lK[buf][chunk * 512]);
      g2lds16(Vb + (size_t)row * 4096 + kt + scol, &lV[buf][chunk * 512]);
    }
  };

  stage(0, 0);
  __syncthreads();  // compiler drains vmcnt(0) before barrier

  for (int t = 0; t < 16; ++t) {
    const int cur = t & 1;
    if (t < 15) stage(cur ^ 1, (t + 1) * 64);

    // S^T = K . Q^T : rows = keys, col = q (lane-local l15); 4 q-groups per kf
    f32x4 st[4][4] = {};
    __builtin_amdgcn_s_setprio(1);
#pragma unroll
    for (int kk = 0; kk < 2; ++kk)
#pragma unroll
      for (int mb = 0; mb < 4; ++mb) {
        bf16x8 kf = *reinterpret_cast<const bf16x8*>(
            &lK[cur][(mb * 16 + l15) * 64 + (((kk * 4 + lg) ^ (l15 & 7)) << 3)]);
        st[0][mb] = MFMA(kf, qf[0][kk], st[0][mb]);
        st[1][mb] = MFMA(kf, qf[1][kk], st[1][mb]);
        st[2][mb] = MFMA(kf, qf[2][kk], st[2][mb]);
        st[3][mb] = MFMA(kf, qf[3][kk], st[3][mb]);
      }
    __builtin_amdgcn_s_setprio(0);

    // P = 2^s directly (no max tracking; bounded scores)
#pragma unroll
    for (int g = 0; g < 4; ++g)
#pragma unroll
      for (int mb = 0; mb < 4; ++mb)
#pragma unroll
        for (int r = 0; r < 4; ++r)
          st[g][mb][r] = FEXP2(st[g][mb][r]);

    // P -> bf16 B-frags in-register (round-6-proven permutation)
    bf16x8 pb[4][2];
#pragma unroll
    for (int g = 0; g < 4; ++g)
#pragma unroll
      for (int kk = 0; kk < 2; ++kk) {
        unsigned A  = cvtpk(st[g][2 * kk][0],     st[g][2 * kk][1]);
        unsigned Ap = cvtpk(st[g][2 * kk][2],     st[g][2 * kk][3]);
        unsigned B  = cvtpk(st[g][2 * kk + 1][0], st[g][2 * kk + 1][1]);
        unsigned Bp = cvtpk(st[g][2 * kk + 1][2], st[g][2 * kk + 1][3]);
        lane_swap32(A, B);
        lane_swap16(A, B);
        lane_swap32(Ap, Bp);
        lane_swap16(Ap, Bp);
        union { unsigned u[4]; bf16x8 v; } pu;
        pu.u[0] = A; pu.u[1] = Ap; pu.u[2] = B; pu.u[3] = Bp;
        pb[g][kk] = pu.v;
      }

    // O^T += V^T . P^T ; l via ones-row MFMA; each vf feeds 4 q-groups
    __builtin_amdgcn_s_setprio(1);
#pragma unroll
    for (int kk = 0; kk < 2; ++kk) {
      lac[0] = MFMA(onesf, pb[0][kk], lac[0]);
      lac[1] = MFMA(onesf, pb[1][kk], lac[1]);
      lac[2] = MFMA(onesf, pb[2][kk], lac[2]);
      lac[3] = MFMA(onesf, pb[3][kk], lac[3]);
#pragma unroll
      for (int hb = 0; hb < 4; ++hb) {
        bf16x8 vf = *reinterpret_cast<const bf16x8*>(
            &lV[cur][(hb * 16 + l15) * 64 + (((kk * 4 + lg) ^ (l15 & 7)) << 3)]);
        oT[0][hb] = MFMA(vf, pb[0][kk], oT[0][hb]);
        oT[1][hb] = MFMA(vf, pb[1][kk], oT[1][hb]);
        oT[2][hb] = MFMA(vf, pb[2][kk], oT[2][hb]);
        oT[3][hb] = MFMA(vf, pb[3][kk], oT[3][hb]);
      }
    }
    __builtin_amdgcn_s_setprio(0);
    __syncthreads();
  }

  // epilogue: store unnormalized partials (l replicated in all lac rows)
#pragma unroll
  for (int g = 0; g < 4; ++g) {
    int q = q0 + wid * 64 + g * 16 + l15;
    size_t rbase = ((size_t)ks * 8 + h) * 4096 + q;
    size_t obase = ((size_t)h * 4096 + q) * 64;
    if (lg == 0) Lp[rbase] = lac[g][0];
#pragma unroll
    for (int hb = 0; hb < 4; ++hb) {
      bf16x4 ov;
#pragma unroll
      for (int r = 0; r < 4; ++r) ov[r] = (bf16_t)oT[g][hb][r];
      *reinterpret_cast<bf16x4*>(Op + obase + hb * 16 + lg * 4) = ov;
    }
  }
}

// ---------------- K-split merge (unweighted; bf16x8-vectorized) ----------------
__global__ __launch_bounds__(256) void k_merge(char* __restrict__ wsb,
                                               const float* __restrict__ Lp,
                                               bf16_t* __restrict__ Obf) {
  int idx = blockIdx.x * 256 + threadIdx.x;  // 8*4096*8 threads
  int d8 = (idx & 7) << 3;
  int row = idx >> 3;  // h*4096 + q
  float l = 0.f;
  float o[8] = {};
#pragma unroll
  for (int s = 0; s < 4; ++s) {
    const bf16_t* Ops = (const bf16_t*)(s < 3 ? wsb + ((size_t)s << 22) : wsb + (29u << 20));
    l += Lp[s * 32768 + row];
    bf16x8 v = *reinterpret_cast<const bf16x8*>(Ops + (size_t)row * 64 + d8);
#pragma unroll
    for (int j = 0; j < 8; ++j) o[j] += (float)v[j];
  }
  float rinv = 1.f / l;
  int h = row >> 12, q = row & 4095;
  bf16x8 ov;
#pragma unroll
  for (int j = 0; j < 8; ++j) ov[j] = (bf16_t)(o[j] * rinv);
  *reinterpret_cast<bf16x8*>(Obf + (size_t)q * 512 + h * 64 + d8) = ov;
}

// ---------------- output GEMM + bias + residual ----------------
__global__ __launch_bounds__(256) void k_gemm_out(const bf16_t* __restrict__ Obf,
                                                  const bf16_t* __restrict__ WoT,
                                                  const float* __restrict__ bo,
                                                  const float* __restrict__ resid,
                                                  float* __restrict__ out) {
  __shared__ bf16_t lA[64 * 64];
  __shared__ bf16_t lB[64 * 64];
  const int m0 = blockIdx.x * 64, n0 = blockIdx.y * 64;
  const int tid = threadIdx.x, lane = tid & 63, wid = tid >> 6;
  const int wr = wid >> 1, wc = wid & 1;
  const int l15 = lane & 15, lg = lane >> 4;
  const int srow = lane >> 3;
  const int scol = ((lane & 7) ^ (lane >> 3)) << 3;

  f32x4 acc[2][2] = {};

  for (int kt = 0; kt < 512; kt += 64) {
#pragma unroll
    for (int i = 0; i < 2; ++i) {
      int chunk = wid * 2 + i;
      int row = chunk * 8 + srow;
      g2lds16(Obf + (size_t)(m0 + row) * 512 + kt + scol, lA + chunk * 512);
      g2lds16(WoT + (size_t)(n0 + row) * 512 + kt + scol, lB + chunk * 512);
    }
    __syncthreads();
#pragma unroll
    for (int kk = 0; kk < 2; ++kk) {
      bf16x8 af[2], bw[2];
      int c16 = ((4 * kk + lg) ^ (l15 & 7)) << 3;
#pragma unroll
      for (int i = 0; i < 2; ++i) {
        af[i] = *reinterpret_cast<const bf16x8*>(lA + (wr * 32 + i * 16 + l15) * 64 + c16);
        bw[i] = *reinterpret_cast<const bf16x8*>(lB + (wc * 32 + i * 16 + l15) * 64 + c16);
      }
#pragma unroll
      for (int i = 0; i < 2; ++i)
#pragma unroll
        for (int j = 0; j < 2; ++j)
          acc[i][j] = MFMA(af[i], bw[j], acc[i][j]);
    }
    __syncthreads();
  }

#pragma unroll
  for (int i = 0; i < 2; ++i)
#pragma unroll
    for (int j = 0; j < 2; ++j)
#pragma unroll
      for (int r = 0; r < 4; ++r) {
        int s = m0 + wr * 32 + i * 16 + lg * 4 + r;
        int n = n0 + wc * 32 + j * 16 + l15;
        size_t o = (size_t)s * 512 + n;
        out[o] = acc[i][j][r] + bo[n] + resid[o];
      }
}

extern "C" void kernel_launch(void* const* d_in, const int* in_sizes, int n_in,
                              void* d_out, int out_size, void* d_ws, size_t ws_size,
                              hipStream_t stream) {
  const float* hs   = (const float*)d_in[0];
  const float* pout = (const float*)d_in[1];
  const float* pinv = (const float*)d_in[2];
  const float* Wq   = (const float*)d_in[3];
  const float* Wk   = (const float*)d_in[4];
  const float* Wv   = (const float*)d_in[5];
  const float* Wo   = (const float*)d_in[6];
  const float* bo   = (const float*)d_in[7];
  float* out = (float*)d_out;

  char* ws = (char*)d_ws;
  bf16_t* Xbf = (bf16_t*)(ws);                          // 4 MB   (Op[0] later)
  bf16_t* WqT = (bf16_t*)(ws + (4u << 20));             // 4 MB   (Op[1] later)
  bf16_t* WkT = (bf16_t*)(ws + (8u << 20));             // 4 MB   (Op[2] later)
  bf16_t* WvT = (bf16_t*)(ws + (12u << 20));            // 0.5 MB (dead after qkv)
  bf16_t* WoT = (bf16_t*)(ws + (12u << 20) + (512u << 10));  // 0.5 MB, live to end
  bf16_t* Qh  = (bf16_t*)(ws + (13u << 20));            // 4 MB (h,s,d)
  bf16_t* Kh  = (bf16_t*)(ws + (17u << 20));            // 4 MB (h,s,d)
  bf16_t* Vt  = (bf16_t*)(ws + (21u << 20));            // 4 MB (h,d,s)
  bf16_t* Obf = (bf16_t*)(ws + (25u << 20));            // 4 MB
  // Op[3] at 29 MB (4 MB), Lp at 33 MB -> peak ~33.5 MB
  float*  Lp  = (float*)(ws + (33u << 20));

  hipLaunchKernelGGL(k_prep, dim3(3328), dim3(256), 0, stream,
                     hs, Wq, Wk, Wv, Wo, pout, pinv, Xbf, WqT, WkT, WvT, WoT);
  hipLaunchKernelGGL(k_gemm_qkv, dim3(32, 8, 3), dim3(256), 0, stream,
                     Xbf, WqT, WkT, WvT, Qh, Kh, Vt);
  hipLaunchKernelGGL(k_attn, dim3(16, 8, 4), dim3(256), 0, stream, Qh, Kh, Vt, ws, Lp);
  hipLaunchKernelGGL(k_merge, dim3(1024), dim3(256), 0, stream, ws, Lp, Obf);
  hipLaunchKernelGGL(k_gemm_out, dim3(64, 8), dim3(256), 0, stream, Obf, WoT, bo, hs, out);
}